// Round 1
// baseline (316.331 us; speedup 1.0000x reference)
//
#include <hip/hip_runtime.h>
#include <hip/hip_bf16.h>

typedef __bf16 bf16x8 __attribute__((ext_vector_type(8)));
typedef float f32x4 __attribute__((ext_vector_type(4)));

#define LOG2E 1.4426950408889634f
#define LAMBDA_INIT 0.3555090675909693f

__device__ __forceinline__ unsigned short f2bf(float f) {
    __hip_bfloat16 h = __float2bfloat16(f);
    unsigned short u;
    __builtin_memcpy(&u, &h, 2);
    return u;
}

// ---------------- QKV projection: (16384 x 1024) @ (1024 x 128) x3 -> bf16 ----------------
__global__ __launch_bounds__(256) void qkv_gemm(
    const float* __restrict__ x, const float* __restrict__ Wq,
    const float* __restrict__ Wk, const float* __restrict__ Wv,
    unsigned short* __restrict__ qkv) {
    const int tid = threadIdx.x;
    const int l = tid & 63, wid = tid >> 6;
    const int g = l >> 4, i16 = l & 15;
    const int row0 = blockIdx.x * 128;
    const int mat = blockIdx.y;
    const float* W = (mat == 0) ? Wq : (mat == 1) ? Wk : Wv;
    unsigned short* out = qkv + (size_t)mat * (16384 * 128);

    __shared__ unsigned short xs[128][72];  // x tile [row][k], pad 72 (144B = 9*16)
    __shared__ unsigned short wt[128][72];  // W transposed [n][k]

    f32x4 acc[2][8];
    const f32x4 z4 = {0.f, 0.f, 0.f, 0.f};
    for (int a = 0; a < 2; ++a)
        for (int b = 0; b < 8; ++b) acc[a][b] = z4;

    for (int k0 = 0; k0 < 1024; k0 += 64) {
        __syncthreads();
        // stage x tile (128 x 64), f32 -> bf16, row-major
        {
            const int c = (tid & 15) * 4;
            const int rbase = tid >> 4;
            for (int it = 0; it < 8; ++it) {
                int r = rbase + it * 16;
                const float4 v = *(const float4*)&x[(size_t)(row0 + r) * 1024 + k0 + c];
                ushort4 pk = make_ushort4(f2bf(v.x), f2bf(v.y), f2bf(v.z), f2bf(v.w));
                *(ushort4*)&xs[r][c] = pk;
            }
        }
        // stage W tile transposed: wt[n][k]
        {
            const int i32 = tid & 31;
            const int n0 = i32 * 4;
            const int kb = tid >> 5;
            for (int it = 0; it < 8; ++it) {
                int kk = it * 8 + kb;
                const float4 v = *(const float4*)&W[(size_t)(k0 + kk) * 128 + n0];
                float vv[4] = {v.x, v.y, v.z, v.w};
                for (int j = 0; j < 4; ++j) {
                    int jj = (j + i32 + kb) & 3;  // rotate to spread banks
                    wt[n0 + jj][kk] = f2bf(vv[jj]);
                }
            }
        }
        __syncthreads();

        bf16x8 af[2][2];
        for (int rb = 0; rb < 2; ++rb)
            for (int c = 0; c < 2; ++c)
                af[rb][c] = *(const bf16x8*)&xs[wid * 32 + rb * 16 + i16][c * 32 + 8 * g];
        for (int nb = 0; nb < 8; ++nb) {
            bf16x8 b0 = *(const bf16x8*)&wt[nb * 16 + i16][8 * g];
            bf16x8 b1 = *(const bf16x8*)&wt[nb * 16 + i16][32 + 8 * g];
            for (int rb = 0; rb < 2; ++rb) {
                acc[rb][nb] = __builtin_amdgcn_mfma_f32_16x16x32_bf16(af[rb][0], b0, acc[rb][nb], 0, 0, 0);
                acc[rb][nb] = __builtin_amdgcn_mfma_f32_16x16x32_bf16(af[rb][1], b1, acc[rb][nb], 0, 0, 0);
            }
        }
    }
    for (int rb = 0; rb < 2; ++rb)
        for (int nb = 0; nb < 8; ++nb)
            for (int r = 0; r < 4; ++r) {
                int row = row0 + wid * 32 + rb * 16 + g * 4 + r;
                int col = nb * 16 + i16;
                out[(size_t)row * 128 + col] = f2bf(acc[rb][nb][r]);
            }
}

// ---------------- Differential causal flash attention ----------------
// grid (64 q-tiles, 4 batches), 256 thr. QBLK=64, KVBLK=64.
// waves 0,1: branch 1 (rows 0-31 / 32-63); waves 2,3: branch 2.
__global__ __launch_bounds__(256) void diff_attn(
    const unsigned short* __restrict__ q, const unsigned short* __restrict__ kk_,
    const unsigned short* __restrict__ vv_,
    const float* __restrict__ lq1, const float* __restrict__ lq2,
    const float* __restrict__ lk1, const float* __restrict__ lk2,
    float* __restrict__ out) {
    const int t = blockIdx.x, b = blockIdx.y;
    const int tid = threadIdx.x;
    const int l = tid & 63, wid = tid >> 6;
    const int g = l >> 4, i16 = l & 15;
    const int branch = wid >> 1, rhalf = wid & 1;
    const float scale = 0.125f;
    const float NEGINF = -__builtin_inff();

    // lambda = exp(lq1.lk1) - exp(lq2.lk2) + lambda_init  (64-elem dots, wave-redundant)
    float s1 = lq1[l] * lk1[l];
    float s2 = lq2[l] * lk2[l];
    for (int off = 32; off > 0; off >>= 1) {
        s1 += __shfl_xor(s1, off);
        s2 += __shfl_xor(s2, off);
    }
    const float lam = exp2f(s1 * LOG2E) - exp2f(s2 * LOG2E) + LAMBDA_INIT;

    __shared__ unsigned short ks[64][136];    // K tile [kv][d0..127], pad 136 (272B)
    __shared__ unsigned short vt[128][72];    // V transposed [dv][kv], pad 72 (144B)
    __shared__ unsigned short ps[4][32][72];  // per-wave P bounce [row][kv]
    __shared__ float ob[64][128];             // branch-2 output for combine

    const size_t bbase = (size_t)b * 4096;
    const int qrow0 = t * 64 + rhalf * 32;

    bf16x8 qf[2][2];
    for (int rb = 0; rb < 2; ++rb)
        for (int c = 0; c < 2; ++c)
            qf[rb][c] = *(const bf16x8*)&q[(bbase + qrow0 + rb * 16 + i16) * 128 + branch * 64 + c * 32 + 8 * g];

    float m_[2][4], lsum[2][4];
    f32x4 acc_o[2][8];
    const f32x4 z4 = {0.f, 0.f, 0.f, 0.f};
    for (int rb = 0; rb < 2; ++rb) {
        for (int r = 0; r < 4; ++r) { m_[rb][r] = NEGINF; lsum[rb][r] = 0.f; }
        for (int nb = 0; nb < 8; ++nb) acc_o[rb][nb] = z4;
    }

    const int str = tid >> 4;        // stage row 0..15
    const int stc = (tid & 15) * 8;  // stage col (elems)
    const int sj = tid & 15;

    for (int s = 0; s <= t; ++s) {
        __syncthreads();
        for (int it = 0; it < 4; ++it) {
            int kv = it * 16 + str;
            const uint4 dk = *(const uint4*)&kk_[(bbase + s * 64 + kv) * 128 + stc];
            *(uint4*)&ks[kv][stc] = dk;
            const uint4 dv = *(const uint4*)&vv_[(bbase + s * 64 + kv) * 128 + stc];
            union { uint4 u; unsigned short e[8]; } uu;
            uu.u = dv;
            for (int j = 0; j < 8; ++j) {
                int jj = (j + sj) & 7;  // rotate lanes to avoid same-bank scatter
                vt[stc + jj][kv] = uu.e[jj];
            }
        }
        __syncthreads();

        // S = Q K^T  (per wave: 32 rows x 64 kv, one branch)
        f32x4 sc[2][4];
        for (int rb = 0; rb < 2; ++rb)
            for (int cb = 0; cb < 4; ++cb) sc[rb][cb] = z4;
        for (int cb = 0; cb < 4; ++cb)
            for (int c = 0; c < 2; ++c) {
                bf16x8 kf = *(const bf16x8*)&ks[cb * 16 + i16][branch * 64 + c * 32 + 8 * g];
                for (int rb = 0; rb < 2; ++rb)
                    sc[rb][cb] = __builtin_amdgcn_mfma_f32_16x16x32_bf16(qf[rb][c], kf, sc[rb][cb], 0, 0, 0);
            }
        // scale + causal mask on diagonal tile
        for (int rb = 0; rb < 2; ++rb)
            for (int cb = 0; cb < 4; ++cb)
                for (int r = 0; r < 4; ++r) sc[rb][cb][r] *= scale;
        if (s == t) {
            for (int rb = 0; rb < 2; ++rb)
                for (int cb = 0; cb < 4; ++cb)
                    for (int r = 0; r < 4; ++r) {
                        int qr = rhalf * 32 + rb * 16 + g * 4 + r;
                        int kc = cb * 16 + i16;
                        if (kc > qr) sc[rb][cb][r] = NEGINF;
                    }
        }
        // online softmax (row groups of 16 lanes share a row)
        for (int rb = 0; rb < 2; ++rb) {
            float mx[4];
            for (int r = 0; r < 4; ++r)
                mx[r] = fmaxf(fmaxf(sc[rb][0][r], sc[rb][1][r]), fmaxf(sc[rb][2][r], sc[rb][3][r]));
            for (int off = 1; off < 16; off <<= 1)
                for (int r = 0; r < 4; ++r) mx[r] = fmaxf(mx[r], __shfl_xor(mx[r], off));
            float al[4];
            for (int r = 0; r < 4; ++r) {
                float mn = fmaxf(m_[rb][r], mx[r]);
                al[r] = exp2f((m_[rb][r] - mn) * LOG2E);
                m_[rb][r] = mn;
            }
            float rs[4] = {0.f, 0.f, 0.f, 0.f};
            for (int cb = 0; cb < 4; ++cb)
                for (int r = 0; r < 4; ++r) {
                    float p = exp2f((sc[rb][cb][r] - m_[rb][r]) * LOG2E);
                    sc[rb][cb][r] = p;
                    rs[r] += p;
                }
            for (int off = 1; off < 16; off <<= 1)
                for (int r = 0; r < 4; ++r) rs[r] += __shfl_xor(rs[r], off);
            for (int r = 0; r < 4; ++r) lsum[rb][r] = lsum[rb][r] * al[r] + rs[r];
            for (int nb = 0; nb < 8; ++nb)
                for (int r = 0; r < 4; ++r) acc_o[rb][nb][r] *= al[r];
            for (int cb = 0; cb < 4; ++cb)
                for (int r = 0; r < 4; ++r)
                    ps[wid][rb * 16 + g * 4 + r][cb * 16 + i16] = f2bf(sc[rb][cb][r]);
        }
        asm volatile("s_waitcnt lgkmcnt(0)" ::: "memory");  // wave-local P write->read
        bf16x8 pa[2][2];
        for (int rb = 0; rb < 2; ++rb)
            for (int c = 0; c < 2; ++c)
                pa[rb][c] = *(const bf16x8*)&ps[wid][rb * 16 + i16][c * 32 + 8 * g];
        for (int nb = 0; nb < 8; ++nb)
            for (int c = 0; c < 2; ++c) {
                bf16x8 vb = *(const bf16x8*)&vt[nb * 16 + i16][c * 32 + 8 * g];
                for (int rb = 0; rb < 2; ++rb)
                    acc_o[rb][nb] = __builtin_amdgcn_mfma_f32_16x16x32_bf16(pa[rb][c], vb, acc_o[rb][nb], 0, 0, 0);
            }
    }

    // combine branches: out = o1/l1 - lam * o2/l2
    __syncthreads();
    if (branch == 1) {
        for (int rb = 0; rb < 2; ++rb)
            for (int nb = 0; nb < 8; ++nb)
                for (int r = 0; r < 4; ++r) {
                    int rl = rhalf * 32 + rb * 16 + g * 4 + r;
                    ob[rl][nb * 16 + i16] = acc_o[rb][nb][r] / lsum[rb][r];
                }
    }
    __syncthreads();
    if (branch == 0) {
        for (int rb = 0; rb < 2; ++rb)
            for (int nb = 0; nb < 8; ++nb)
                for (int r = 0; r < 4; ++r) {
                    int rl = rhalf * 32 + rb * 16 + g * 4 + r;
                    float o2 = ob[rl][nb * 16 + i16];
                    float val = acc_o[rb][nb][r] / lsum[rb][r] - lam * o2;
                    out[(bbase + t * 64 + rl) * 128 + nb * 16 + i16] = val;
                }
    }
}

extern "C" void kernel_launch(void* const* d_in, const int* in_sizes, int n_in,
                              void* d_out, int out_size, void* d_ws, size_t ws_size,
                              hipStream_t stream) {
    const float* x   = (const float*)d_in[0];
    const float* Wq  = (const float*)d_in[1];
    const float* Wk  = (const float*)d_in[2];
    const float* Wv  = (const float*)d_in[3];
    const float* lq1 = (const float*)d_in[4];
    const float* lq2 = (const float*)d_in[5];
    const float* lk1 = (const float*)d_in[6];
    const float* lk2 = (const float*)d_in[7];
    float* out = (float*)d_out;
    unsigned short* qkv = (unsigned short*)d_ws;

    qkv_gemm<<<dim3(128, 3), 256, 0, stream>>>(x, Wq, Wk, Wv, qkv);

    const unsigned short* qb = qkv;
    const unsigned short* kb = qkv + (size_t)16384 * 128;
    const unsigned short* vb = qkv + (size_t)2 * 16384 * 128;
    diff_attn<<<dim3(64, 4), 256, 0, stream>>>(qb, kb, vb, lq1, lq2, lk1, lk2, out);
}

// Round 2
// 222.055 us; speedup vs baseline: 1.4246x; 1.4246x over previous
//
#include <hip/hip_runtime.h>
#include <hip/hip_bf16.h>

typedef __bf16 bf16x8 __attribute__((ext_vector_type(8)));
typedef float f32x4 __attribute__((ext_vector_type(4)));

#define LOG2E 1.4426950408889634f
#define LAMBDA_INIT 0.3555090675909693f

// ws layout: [0, 12.58MB) qkv bf16 ; [12.58MB, +34.1MB) partials f32
#define QKV_ELEMS ((size_t)3 * 16384 * 128)
#define REC_FLOATS 8320  // m[64] l[64] O[64*128]

__device__ __forceinline__ unsigned short f2bf(float f) {
    __hip_bfloat16 h = __float2bfloat16(f);
    unsigned short u;
    __builtin_memcpy(&u, &h, 2);
    return u;
}

// ---------------- QKV projection: (16384 x 1024) @ (1024 x 128) x3 -> bf16 ----------------
__global__ __launch_bounds__(256) void qkv_gemm(
    const float* __restrict__ x, const float* __restrict__ Wq,
    const float* __restrict__ Wk, const float* __restrict__ Wv,
    unsigned short* __restrict__ qkv) {
    const int tid = threadIdx.x;
    const int l = tid & 63, wid = tid >> 6;
    const int g = l >> 4, i16 = l & 15;
    const int row0 = blockIdx.x * 128;
    const int mat = blockIdx.y;
    const float* W = (mat == 0) ? Wq : (mat == 1) ? Wk : Wv;
    unsigned short* out = qkv + (size_t)mat * (16384 * 128);

    __shared__ unsigned short xs[128][72];
    __shared__ unsigned short wt[128][72];

    f32x4 acc[2][8];
    const f32x4 z4 = {0.f, 0.f, 0.f, 0.f};
    for (int a = 0; a < 2; ++a)
        for (int b = 0; b < 8; ++b) acc[a][b] = z4;

    for (int k0 = 0; k0 < 1024; k0 += 64) {
        __syncthreads();
        {
            const int c = (tid & 15) * 4;
            const int rbase = tid >> 4;
            for (int it = 0; it < 8; ++it) {
                int r = rbase + it * 16;
                const float4 v = *(const float4*)&x[(size_t)(row0 + r) * 1024 + k0 + c];
                ushort4 pk = make_ushort4(f2bf(v.x), f2bf(v.y), f2bf(v.z), f2bf(v.w));
                *(ushort4*)&xs[r][c] = pk;
            }
        }
        {
            const int i32 = tid & 31;
            const int n0 = i32 * 4;
            const int kb = tid >> 5;
            for (int it = 0; it < 8; ++it) {
                int kk = it * 8 + kb;
                const float4 v = *(const float4*)&W[(size_t)(k0 + kk) * 128 + n0];
                float vv[4] = {v.x, v.y, v.z, v.w};
                for (int j = 0; j < 4; ++j) {
                    int jj = (j + i32 + kb) & 3;
                    wt[n0 + jj][kk] = f2bf(vv[jj]);
                }
            }
        }
        __syncthreads();

        bf16x8 af[2][2];
        for (int rb = 0; rb < 2; ++rb)
            for (int c = 0; c < 2; ++c)
                af[rb][c] = *(const bf16x8*)&xs[wid * 32 + rb * 16 + i16][c * 32 + 8 * g];
        for (int nb = 0; nb < 8; ++nb) {
            bf16x8 b0 = *(const bf16x8*)&wt[nb * 16 + i16][8 * g];
            bf16x8 b1 = *(const bf16x8*)&wt[nb * 16 + i16][32 + 8 * g];
            for (int rb = 0; rb < 2; ++rb) {
                acc[rb][nb] = __builtin_amdgcn_mfma_f32_16x16x32_bf16(af[rb][0], b0, acc[rb][nb], 0, 0, 0);
                acc[rb][nb] = __builtin_amdgcn_mfma_f32_16x16x32_bf16(af[rb][1], b1, acc[rb][nb], 0, 0, 0);
            }
        }
    }
    for (int rb = 0; rb < 2; ++rb)
        for (int nb = 0; nb < 8; ++nb)
            for (int r = 0; r < 4; ++r) {
                int row = row0 + wid * 32 + rb * 16 + g * 4 + r;
                int col = nb * 16 + i16;
                out[(size_t)row * 128 + col] = f2bf(acc[rb][nb][r]);
            }
}

// ---------------- Differential causal flash attention, kv-split ----------------
// grid (64 q-tiles, 4 batches, 2 kv-chunks), 256 thr. QBLK=64, KVBLK=64.
// waves 0,1: branch 1 (rows 0-31 / 32-63); waves 2,3: branch 2.
// Writes unnormalized partials (m, l, O) per (b, t, chunk, branch).
__global__ __launch_bounds__(256) void diff_attn_split(
    const unsigned short* __restrict__ q, const unsigned short* __restrict__ kk_,
    const unsigned short* __restrict__ vv_,
    float* __restrict__ part) {
    const int bx = blockIdx.x, b = blockIdx.y, c = blockIdx.z;
    const int t = c ? (63 - bx) : bx;  // reversed for chunk1: balances (i, i+256) CU pairs
    const int n = t + 1, n0 = (n + 1) >> 1;
    const int s_lo = c ? n0 : 0, s_hi = c ? n : n0;

    const int tid = threadIdx.x;
    const int l = tid & 63, wid = tid >> 6;
    const int g = l >> 4, i16 = l & 15;
    const int branch = wid >> 1, rhalf = wid & 1;
    const float scale = 0.125f;
    const float NEGINF = -__builtin_inff();

    __shared__ unsigned short ks[64][136];    // K tile [kv][d], pad 136
    __shared__ unsigned short vt[128][72];    // V transposed [dv][kv], pad 72
    __shared__ unsigned short ps[4][32][72];  // per-wave P bounce

    const size_t bbase = (size_t)b * 4096;
    const int qrow0 = t * 64 + rhalf * 32;

    bf16x8 qf[2][2];
    for (int rb = 0; rb < 2; ++rb)
        for (int cc = 0; cc < 2; ++cc)
            qf[rb][cc] = *(const bf16x8*)&q[(bbase + qrow0 + rb * 16 + i16) * 128 + branch * 64 + cc * 32 + 8 * g];

    float m_[2][4], lsum[2][4];
    f32x4 acc_o[2][8];
    const f32x4 z4 = {0.f, 0.f, 0.f, 0.f};
    for (int rb = 0; rb < 2; ++rb) {
        for (int r = 0; r < 4; ++r) { m_[rb][r] = NEGINF; lsum[rb][r] = 0.f; }
        for (int nb = 0; nb < 8; ++nb) acc_o[rb][nb] = z4;
    }

    const int str = tid >> 4;
    const int stc = (tid & 15) * 8;
    const int sj = tid & 15;

    for (int s = s_lo; s < s_hi; ++s) {
        __syncthreads();
        for (int it = 0; it < 4; ++it) {
            int kv = it * 16 + str;
            const uint4 dk = *(const uint4*)&kk_[(bbase + s * 64 + kv) * 128 + stc];
            *(uint4*)&ks[kv][stc] = dk;
            const uint4 dv = *(const uint4*)&vv_[(bbase + s * 64 + kv) * 128 + stc];
            union { uint4 u; unsigned short e[8]; } uu;
            uu.u = dv;
            for (int j = 0; j < 8; ++j) {
                int jj = (j + sj) & 7;
                vt[stc + jj][kv] = uu.e[jj];
            }
        }
        __syncthreads();

        f32x4 sc[2][4];
        for (int rb = 0; rb < 2; ++rb)
            for (int cb = 0; cb < 4; ++cb) sc[rb][cb] = z4;
        for (int cb = 0; cb < 4; ++cb)
            for (int cc = 0; cc < 2; ++cc) {
                bf16x8 kf = *(const bf16x8*)&ks[cb * 16 + i16][branch * 64 + cc * 32 + 8 * g];
                for (int rb = 0; rb < 2; ++rb)
                    sc[rb][cb] = __builtin_amdgcn_mfma_f32_16x16x32_bf16(qf[rb][cc], kf, sc[rb][cb], 0, 0, 0);
            }
        for (int rb = 0; rb < 2; ++rb)
            for (int cb = 0; cb < 4; ++cb)
                for (int r = 0; r < 4; ++r) sc[rb][cb][r] *= scale;
        if (s == t) {
            for (int rb = 0; rb < 2; ++rb)
                for (int cb = 0; cb < 4; ++cb)
                    for (int r = 0; r < 4; ++r) {
                        int qr = rhalf * 32 + rb * 16 + g * 4 + r;
                        int kc = cb * 16 + i16;
                        if (kc > qr) sc[rb][cb][r] = NEGINF;
                    }
        }
        for (int rb = 0; rb < 2; ++rb) {
            float mx[4];
            for (int r = 0; r < 4; ++r)
                mx[r] = fmaxf(fmaxf(sc[rb][0][r], sc[rb][1][r]), fmaxf(sc[rb][2][r], sc[rb][3][r]));
            for (int off = 1; off < 16; off <<= 1)
                for (int r = 0; r < 4; ++r) mx[r] = fmaxf(mx[r], __shfl_xor(mx[r], off));
            float al[4];
            for (int r = 0; r < 4; ++r) {
                float mn = fmaxf(m_[rb][r], mx[r]);
                al[r] = exp2f((m_[rb][r] - mn) * LOG2E);
                m_[rb][r] = mn;
            }
            float rs[4] = {0.f, 0.f, 0.f, 0.f};
            for (int cb = 0; cb < 4; ++cb)
                for (int r = 0; r < 4; ++r) {
                    float p = exp2f((sc[rb][cb][r] - m_[rb][r]) * LOG2E);
                    sc[rb][cb][r] = p;
                    rs[r] += p;
                }
            for (int off = 1; off < 16; off <<= 1)
                for (int r = 0; r < 4; ++r) rs[r] += __shfl_xor(rs[r], off);
            for (int r = 0; r < 4; ++r) lsum[rb][r] = lsum[rb][r] * al[r] + rs[r];
            for (int nb = 0; nb < 8; ++nb)
                for (int r = 0; r < 4; ++r) acc_o[rb][nb][r] *= al[r];
            for (int cb = 0; cb < 4; ++cb)
                for (int r = 0; r < 4; ++r)
                    ps[wid][rb * 16 + g * 4 + r][cb * 16 + i16] = f2bf(sc[rb][cb][r]);
        }
        asm volatile("s_waitcnt lgkmcnt(0)" ::: "memory");
        bf16x8 pa[2][2];
        for (int rb = 0; rb < 2; ++rb)
            for (int cc = 0; cc < 2; ++cc)
                pa[rb][cc] = *(const bf16x8*)&ps[wid][rb * 16 + i16][cc * 32 + 8 * g];
        for (int nb = 0; nb < 8; ++nb)
            for (int cc = 0; cc < 2; ++cc) {
                bf16x8 vb = *(const bf16x8*)&vt[nb * 16 + i16][cc * 32 + 8 * g];
                for (int rb = 0; rb < 2; ++rb)
                    acc_o[rb][nb] = __builtin_amdgcn_mfma_f32_16x16x32_bf16(pa[rb][cc], vb, acc_o[rb][nb], 0, 0, 0);
            }
    }

    // store partial (m, l, unnormalized O)
    float* rec = part + ((((size_t)b * 64 + t) * 2 + c) * 2 + branch) * REC_FLOATS;
    for (int rb = 0; rb < 2; ++rb) {
        if (i16 == 0)
            for (int r = 0; r < 4; ++r) {
                int row = rhalf * 32 + rb * 16 + g * 4 + r;
                rec[row] = m_[rb][r];
                rec[64 + row] = lsum[rb][r];
            }
        for (int nb = 0; nb < 8; ++nb)
            for (int r = 0; r < 4; ++r) {
                int row = rhalf * 32 + rb * 16 + g * 4 + r;
                rec[128 + row * 128 + nb * 16 + i16] = acc_o[rb][nb][r];
            }
    }
}

// ---------------- combine: merge 2 chunks per branch, normalize, o1 - lam*o2 ----------------
__global__ __launch_bounds__(256) void diff_combine(
    const float* __restrict__ part,
    const float* __restrict__ lq1, const float* __restrict__ lq2,
    const float* __restrict__ lk1, const float* __restrict__ lk2,
    float* __restrict__ out) {
    const int t = blockIdx.x, b = blockIdx.y;
    const int tid = threadIdx.x;
    __shared__ float sm[2][2][64], sl[2][2][64];  // [branch][chunk][row]
    __shared__ float s_lam;

    if (tid < 64) {
        float s1 = lq1[tid] * lk1[tid];
        float s2 = lq2[tid] * lk2[tid];
        for (int off = 32; off > 0; off >>= 1) {
            s1 += __shfl_xor(s1, off);
            s2 += __shfl_xor(s2, off);
        }
        if (tid == 0) s_lam = expf(s1) - expf(s2) + LAMBDA_INIT;
    }
    {
        int r = tid & 63, br = (tid >> 6) & 1, cc = tid >> 7;
        const float* rec = part + ((((size_t)b * 64 + t) * 2 + cc) * 2 + br) * REC_FLOATS;
        sm[br][cc][r] = rec[r];
        sl[br][cc][r] = rec[64 + r];
    }
    __syncthreads();
    const float lam = s_lam;
    const size_t base = (((size_t)b * 64 + t) * 2) * 2 * REC_FLOATS + 128;
    const float* o00 = part + base;                   // c0 br0
    const float* o01 = part + base + REC_FLOATS;      // c0 br1
    const float* o10 = part + base + 2 * REC_FLOATS;  // c1 br0
    const float* o11 = part + base + 3 * REC_FLOATS;  // c1 br1

    float* op = out + ((size_t)b * 4096 + (size_t)t * 64) * 128;
    for (int e = tid; e < 8192; e += 256) {
        int row = e >> 7;
        float m0 = sm[0][0][row], m1 = sm[0][1][row];
        float M = fmaxf(m0, m1);
        float w0 = expf(m0 - M), w1 = expf(m1 - M);
        float linv = 1.0f / (w0 * sl[0][0][row] + w1 * sl[0][1][row]);
        float o1 = (w0 * o00[e] + w1 * o10[e]) * linv;
        m0 = sm[1][0][row]; m1 = sm[1][1][row];
        M = fmaxf(m0, m1);
        w0 = expf(m0 - M); w1 = expf(m1 - M);
        linv = 1.0f / (w0 * sl[1][0][row] + w1 * sl[1][1][row]);
        float o2 = (w0 * o01[e] + w1 * o11[e]) * linv;
        op[e] = o1 - lam * o2;
    }
}

extern "C" void kernel_launch(void* const* d_in, const int* in_sizes, int n_in,
                              void* d_out, int out_size, void* d_ws, size_t ws_size,
                              hipStream_t stream) {
    const float* x   = (const float*)d_in[0];
    const float* Wq  = (const float*)d_in[1];
    const float* Wk  = (const float*)d_in[2];
    const float* Wv  = (const float*)d_in[3];
    const float* lq1 = (const float*)d_in[4];
    const float* lq2 = (const float*)d_in[5];
    const float* lk1 = (const float*)d_in[6];
    const float* lk2 = (const float*)d_in[7];
    float* out = (float*)d_out;
    unsigned short* qkv = (unsigned short*)d_ws;
    float* part = (float*)((char*)d_ws + QKV_ELEMS * 2);

    qkv_gemm<<<dim3(128, 3), 256, 0, stream>>>(x, Wq, Wk, Wv, qkv);

    const unsigned short* qb = qkv;
    const unsigned short* kb = qkv + (size_t)16384 * 128;
    const unsigned short* vb = qkv + (size_t)2 * 16384 * 128;
    diff_attn_split<<<dim3(64, 4, 2), 256, 0, stream>>>(qb, kb, vb, part);
    diff_combine<<<dim3(64, 4), 256, 0, stream>>>(part, lq1, lq2, lk1, lk2, out);
}